// Round 1
// baseline (115.729 us; speedup 1.0000x reference)
//
#include <hip/hip_runtime.h>

constexpr int kNodes = 50000;
constexpr int kEdges = 500000;
constexpr int kInF   = 128;
constexpr int kOutF  = 16;

// ---------------------------------------------------------------------------
// Kernel 1: support[n][f] = sum_k x[n][k] * W[k][f]
// One thread per node; W (128x16 = 8 KB) staged in LDS, broadcast reads.
// ---------------------------------------------------------------------------
__global__ __launch_bounds__(256) void support_kernel(
    const float* __restrict__ x, const float* __restrict__ weight,
    float* __restrict__ support) {
  __shared__ float4 w4[kInF][kOutF / 4];  // w4[k][f4] = weight[k][4*f4 .. 4*f4+3]
  for (int i = threadIdx.x; i < kInF * (kOutF / 4); i += 256) {
    w4[i / (kOutF / 4)][i % (kOutF / 4)] =
        reinterpret_cast<const float4*>(weight)[i];
  }
  __syncthreads();

  const int node = blockIdx.x * 256 + threadIdx.x;
  if (node >= kNodes) return;

  float4 a0 = {0.f, 0.f, 0.f, 0.f};
  float4 a1 = {0.f, 0.f, 0.f, 0.f};
  float4 a2 = {0.f, 0.f, 0.f, 0.f};
  float4 a3 = {0.f, 0.f, 0.f, 0.f};

  const float4* xr = reinterpret_cast<const float4*>(x + (size_t)node * kInF);
#pragma unroll
  for (int k4 = 0; k4 < kInF / 4; ++k4) {
    const float4 v = xr[k4];
    const float vk[4] = {v.x, v.y, v.z, v.w};
#pragma unroll
    for (int kk = 0; kk < 4; ++kk) {
      const int k = k4 * 4 + kk;
      const float s = vk[kk];
      const float4 w0 = w4[k][0];
      const float4 w1 = w4[k][1];
      const float4 w2 = w4[k][2];
      const float4 w3 = w4[k][3];
      a0.x += s * w0.x; a0.y += s * w0.y; a0.z += s * w0.z; a0.w += s * w0.w;
      a1.x += s * w1.x; a1.y += s * w1.y; a1.z += s * w1.z; a1.w += s * w1.w;
      a2.x += s * w2.x; a2.y += s * w2.y; a2.z += s * w2.z; a2.w += s * w2.w;
      a3.x += s * w3.x; a3.y += s * w3.y; a3.z += s * w3.z; a3.w += s * w3.w;
    }
  }

  float4* sp = reinterpret_cast<float4*>(support + (size_t)node * kOutF);
  sp[0] = a0; sp[1] = a1; sp[2] = a2; sp[3] = a3;
}

// ---------------------------------------------------------------------------
// Kernel 2: out[n][f] = bias[f]   (accumulation base; bias added exactly once)
// ---------------------------------------------------------------------------
__global__ __launch_bounds__(256) void init_out_kernel(
    const float* __restrict__ bias, float* __restrict__ out) {
  const int i = blockIdx.x * 256 + threadIdx.x;
  if (i < kNodes * kOutF) out[i] = bias[i & (kOutF - 1)];
}

// ---------------------------------------------------------------------------
// Kernel 3: for each edge e: msg[i] = sum_j edge_data[e][i][j] * support[src][j]
//           atomicAdd(out[tgt][i], msg[i])
// 16 lanes per edge; lane i owns output row i. edge_data read is the 512 MB
// stream that bounds the kernel.
// ---------------------------------------------------------------------------
__global__ __launch_bounds__(256) void edge_kernel(
    const float* __restrict__ edge_data, const float* __restrict__ support,
    const int* __restrict__ esrc, const int* __restrict__ etgt,
    float* __restrict__ out) {
  const int gid = blockIdx.x * 256 + threadIdx.x;
  const int e = gid >> 4;
  const int i = gid & 15;
  if (e >= kEdges) return;

  const int src = esrc[e];
  const int tgt = etgt[e];

  const float4* s4 =
      reinterpret_cast<const float4*>(support + (size_t)src * kOutF);
  const float4 s0 = s4[0], s1 = s4[1], s2 = s4[2], s3 = s4[3];

  const float4* ed = reinterpret_cast<const float4*>(
      edge_data + (size_t)e * (kOutF * kOutF) + (size_t)i * kOutF);
  const float4 r0 = ed[0], r1 = ed[1], r2 = ed[2], r3 = ed[3];

  float acc = r0.x * s0.x + r0.y * s0.y + r0.z * s0.z + r0.w * s0.w;
  acc      += r1.x * s1.x + r1.y * s1.y + r1.z * s1.z + r1.w * s1.w;
  acc      += r2.x * s2.x + r2.y * s2.y + r2.z * s2.z + r2.w * s2.w;
  acc      += r3.x * s3.x + r3.y * s3.y + r3.z * s3.z + r3.w * s3.w;

  atomicAdd(&out[(size_t)tgt * kOutF + i], acc);
}

// ---------------------------------------------------------------------------
extern "C" void kernel_launch(void* const* d_in, const int* in_sizes, int n_in,
                              void* d_out, int out_size, void* d_ws,
                              size_t ws_size, hipStream_t stream) {
  const float* x         = (const float*)d_in[0];
  const float* weight    = (const float*)d_in[1];
  const float* bias      = (const float*)d_in[2];
  const float* edge_data = (const float*)d_in[3];
  const int*   esrc      = (const int*)d_in[4];
  const int*   etgt      = (const int*)d_in[5];
  float* out = (float*)d_out;

  float* support = (float*)d_ws;  // kNodes * kOutF * 4 B = 3.2 MB

  support_kernel<<<(kNodes + 255) / 256, 256, 0, stream>>>(x, weight, support);
  init_out_kernel<<<(kNodes * kOutF + 255) / 256, 256, 0, stream>>>(bias, out);
  edge_kernel<<<(kEdges * 16 + 255) / 256, 256, 0, stream>>>(
      edge_data, support, esrc, etgt, out);
}